// Round 1
// baseline (166.181 us; speedup 1.0000x reference)
//
#include <hip/hip_runtime.h>
#include <math.h>

#define DIM 4096
#define NQ 12
#define NLAYERS 5
#define TPB 256
#define NGATES 72   // 6 layers x 12 qubits

__device__ __forceinline__ float2 cmul(float2 a, float2 b) {
    return make_float2(a.x * b.x - a.y * b.y, a.x * b.y + a.y * b.x);
}
__device__ __forceinline__ float2 cadd(float2 a, float2 b) {
    return make_float2(a.x + b.x, a.y + b.y);
}

// C = A * B  (2x2 complex, row-major [4])
__device__ __forceinline__ void mat2mul(const float2 A[4], const float2 B[4], float2 C[4]) {
    C[0] = cadd(cmul(A[0], B[0]), cmul(A[1], B[2]));
    C[1] = cadd(cmul(A[0], B[1]), cmul(A[1], B[3]));
    C[2] = cadd(cmul(A[2], B[0]), cmul(A[3], B[2]));
    C[3] = cadd(cmul(A[2], B[1]), cmul(A[3], B[3]));
}

__global__ __launch_bounds__(TPB) void qsim_kernel(const float* __restrict__ x,
                                                   const float* __restrict__ w,
                                                   float* __restrict__ out) {
    __shared__ float2 state[DIM];          // 32 KB
    __shared__ float2 gmat[NGATES * 4];    // 2.25 KB
    __shared__ unsigned short perm[DIM];   // 8 KB
    __shared__ float red[4];

    const int tid = threadIdx.x;
    const int b = blockIdx.x;

    // ---- build fused per-qubit gate matrices (threads 0..71) ----
    if (tid < NGATES) {
        const int l = tid / NQ;
        const int q = tid % NQ;
        const float* pp = w + (l < NLAYERS ? l * (3 * NQ) : NLAYERS * (3 * NQ)) + q * 3;
        const float p0 = pp[0], p1 = pp[1], p2 = pp[2];
        float s0, c0, s1, c1, s2, c2;
        sincosf(0.5f * p0, &s0, &c0);
        sincosf(0.5f * p1, &s1, &c1);
        sincosf(0.5f * p2, &s2, &c2);
        float2 U[4], M[4];
        if (l < NLAYERS) {
            // U = Rz(p2) * Ry(p1) * Rx(p0)
            float2 RX[4] = { {c0, 0.f}, {0.f, -s0}, {0.f, -s0}, {c0, 0.f} };
            float2 RY[4] = { {c1, 0.f}, {-s1, 0.f}, {s1, 0.f}, {c1, 0.f} };
            float2 RZ[4] = { {c2, -s2}, {0.f, 0.f}, {0.f, 0.f}, {c2, s2} };
            mat2mul(RY, RX, M);
            mat2mul(RZ, M, U);
        } else {
            // U = Ry(p2) * Rz(p1) * Ry(p0)
            float2 RY0[4] = { {c0, 0.f}, {-s0, 0.f}, {s0, 0.f}, {c0, 0.f} };
            float2 RZ1[4] = { {c1, -s1}, {0.f, 0.f}, {0.f, 0.f}, {c1, s1} };
            float2 RY2[4] = { {c2, 0.f}, {-s2, 0.f}, {s2, 0.f}, {c2, 0.f} };
            mat2mul(RZ1, RY0, M);
            mat2mul(RY2, M, U);
        }
        gmat[tid * 4 + 0] = U[0];
        gmat[tid * 4 + 1] = U[1];
        gmat[tid * 4 + 2] = U[2];
        gmat[tid * 4 + 3] = U[3];
    }

    // ---- ring-of-CNOT composed permutation table (same for every layer) ----
    // state_after[i] = state_before[perm[i]]
    for (int k = 0; k < 16; ++k) {
        int i = tid + k * TPB;
        int y = i;
        // gates applied in order q=0..11; read-index composition applies q=11 first
        for (int q = NQ - 1; q >= 0; --q) {
            int bc = NQ - 1 - q;                 // control bit position
            int bt = NQ - 1 - ((q + 1) % NQ);    // target bit position
            y ^= ((y >> bc) & 1) << bt;
        }
        perm[i] = (unsigned short)y;
    }

    // ---- load x, compute sum of squares ----
    const float* xb = x + (size_t)b * DIM;
    float vals[16];
    float ss = 0.f;
    for (int k = 0; k < 4; ++k) {
        float4 v = reinterpret_cast<const float4*>(xb)[tid + k * TPB];
        vals[k * 4 + 0] = v.x; vals[k * 4 + 1] = v.y;
        vals[k * 4 + 2] = v.z; vals[k * 4 + 3] = v.w;
        ss += v.x * v.x + v.y * v.y + v.z * v.z + v.w * v.w;
    }
    #pragma unroll
    for (int off = 32; off > 0; off >>= 1) ss += __shfl_down(ss, off, 64);
    if ((tid & 63) == 0) red[tid >> 6] = ss;
    __syncthreads();   // also covers gmat + perm writes

    const float total = red[0] + red[1] + red[2] + red[3];
    const float norm = sqrtf(total);
    const float inv = 1.0f / sqrtf(norm + 1e-12f);

    for (int k = 0; k < 4; ++k) {
        int i4 = tid + k * TPB;
        for (int j = 0; j < 4; ++j) {
            state[i4 * 4 + j] = make_float2(vals[k * 4 + j] * inv, 0.f);
        }
    }
    __syncthreads();

    // ---- circuit ----
    for (int l = 0; l < NLAYERS; ++l) {
        for (int q = 0; q < NQ; ++q) {
            const int bpos = NQ - 1 - q;
            const int g = l * NQ + q;
            const float2 u00 = gmat[g * 4 + 0];
            const float2 u01 = gmat[g * 4 + 1];
            const float2 u10 = gmat[g * 4 + 2];
            const float2 u11 = gmat[g * 4 + 3];
            const int mask = (1 << bpos) - 1;
            #pragma unroll
            for (int k = 0; k < 8; ++k) {
                int p = tid + k * TPB;
                int i0 = ((p & ~mask) << 1) | (p & mask);
                int i1 = i0 | (1 << bpos);
                float2 s0 = state[i0];
                float2 s1 = state[i1];
                state[i0] = cadd(cmul(u00, s0), cmul(u01, s1));
                state[i1] = cadd(cmul(u10, s0), cmul(u11, s1));
            }
            __syncthreads();
        }
        // ring of CNOTs: one permutation pass
        float2 tmp[16];
        #pragma unroll
        for (int k = 0; k < 16; ++k) {
            int i = tid + k * TPB;
            tmp[k] = state[perm[i]];
        }
        __syncthreads();
        #pragma unroll
        for (int k = 0; k < 16; ++k) {
            state[tid + k * TPB] = tmp[k];
        }
        __syncthreads();
    }

    // final YZY layer
    for (int q = 0; q < NQ; ++q) {
        const int bpos = NQ - 1 - q;
        const int g = NLAYERS * NQ + q;
        const float2 u00 = gmat[g * 4 + 0];
        const float2 u01 = gmat[g * 4 + 1];
        const float2 u10 = gmat[g * 4 + 2];
        const float2 u11 = gmat[g * 4 + 3];
        const int mask = (1 << bpos) - 1;
        #pragma unroll
        for (int k = 0; k < 8; ++k) {
            int p = tid + k * TPB;
            int i0 = ((p & ~mask) << 1) | (p & mask);
            int i1 = i0 | (1 << bpos);
            float2 s0 = state[i0];
            float2 s1 = state[i1];
            state[i0] = cadd(cmul(u00, s0), cadd(cmul(u01, s1), make_float2(0.f, 0.f)));
            state[i1] = cadd(cmul(u10, s0), cmul(u11, s1));
        }
        __syncthreads();
    }

    // ---- write real part ----
    float* ob = out + (size_t)b * DIM;
    for (int k = 0; k < 4; ++k) {
        int i4 = tid + k * TPB;
        float4 o;
        o.x = state[i4 * 4 + 0].x;
        o.y = state[i4 * 4 + 1].x;
        o.z = state[i4 * 4 + 2].x;
        o.w = state[i4 * 4 + 3].x;
        reinterpret_cast<float4*>(ob)[i4] = o;
    }
}

extern "C" void kernel_launch(void* const* d_in, const int* in_sizes, int n_in,
                              void* d_out, int out_size, void* d_ws, size_t ws_size,
                              hipStream_t stream) {
    const float* x = (const float*)d_in[0];      // [1024, 4096] f32
    const float* w = (const float*)d_in[1];      // [216] f32
    float* out = (float*)d_out;                  // [1024, 4096] f32
    qsim_kernel<<<dim3(1024), dim3(TPB), 0, stream>>>(x, w, out);
}

// Round 2
// 91.563 us; speedup vs baseline: 1.8149x; 1.8149x over previous
//
#include <hip/hip_runtime.h>
#include <math.h>

#define DIM 4096
#define NQ 12
#define NLAYERS 5
#define TPB 256
#define NGATES 72   // 6 layers x 12 qubits

__device__ __forceinline__ float2 cmul(float2 a, float2 b) {
    return make_float2(a.x * b.x - a.y * b.y, a.x * b.y + a.y * b.x);
}
__device__ __forceinline__ float2 cadd(float2 a, float2 b) {
    return make_float2(a.x + b.x, a.y + b.y);
}
__device__ __forceinline__ void mat2mul(const float2 A[4], const float2 B[4], float2 C[4]) {
    C[0] = cadd(cmul(A[0], B[0]), cmul(A[1], B[2]));
    C[1] = cadd(cmul(A[0], B[1]), cmul(A[1], B[3]));
    C[2] = cadd(cmul(A[2], B[0]), cmul(A[3], B[2]));
    C[3] = cadd(cmul(A[2], B[1]), cmul(A[3], B[3]));
}

// Apply a 2x2 gate on local bit LB of the 16 register-resident amplitudes.
template<int LB>
__device__ __forceinline__ void gate_on_bit(float2 (&r)[16], const float2* __restrict__ g) {
    const float2 u00 = g[0], u01 = g[1], u10 = g[2], u11 = g[3];
    constexpr int m = 1 << LB;
    #pragma unroll
    for (int j = 0; j < 16; ++j) {
        if (!(j & m)) {
            const float2 s0 = r[j], s1 = r[j + m];
            float2 n0, n1;
            n0.x = u00.x * s0.x - u00.y * s0.y + u01.x * s1.x - u01.y * s1.y;
            n0.y = u00.x * s0.y + u00.y * s0.x + u01.x * s1.y + u01.y * s1.x;
            n1.x = u10.x * s0.x - u10.y * s0.y + u11.x * s1.x - u11.y * s1.y;
            n1.y = u10.x * s0.y + u10.y * s0.x + u11.x * s1.y + u11.y * s1.x;
            r[j] = n0; r[j + m] = n1;
        }
    }
}

// Phase with global bit base BETA (0=C,4=B,8=A): local bit lb -> global bit
// b = BETA+lb -> qubit q = 11-b -> gate index goff + (11-BETA-lb).
template<int BETA>
__device__ __forceinline__ void apply_phase(float2 (&r)[16], const float2* __restrict__ gm, int goff) {
    gate_on_bit<0>(r, gm + 4 * (goff + 11 - BETA - 0));
    gate_on_bit<1>(r, gm + 4 * (goff + 11 - BETA - 1));
    gate_on_bit<2>(r, gm + 4 * (goff + 11 - BETA - 2));
    gate_on_bit<3>(r, gm + 4 * (goff + 11 - BETA - 3));
}

__global__ __launch_bounds__(TPB) void qsim_kernel(const float* __restrict__ x,
                                                   const float* __restrict__ w,
                                                   float* __restrict__ out) {
    // XOR bank-swizzled state buffer: amplitude i lives at slot S(i) = i ^ ((i>>3)&14)
    __shared__ __align__(16) float2 st[DIM];   // 32 KB
    __shared__ float2 gmat[NGATES * 4];        // 2.25 KB
    __shared__ float red[4];

    const int tid = threadIdx.x;
    const int b = blockIdx.x;

    // ---- build fused per-qubit gate matrices (threads 0..71) ----
    if (tid < NGATES) {
        const int l = tid / NQ;
        const int q = tid % NQ;
        const float* pp = w + (l < NLAYERS ? l * (3 * NQ) : NLAYERS * (3 * NQ)) + q * 3;
        const float p0 = pp[0], p1 = pp[1], p2 = pp[2];
        float s0, c0, s1, c1, s2, c2;
        sincosf(0.5f * p0, &s0, &c0);
        sincosf(0.5f * p1, &s1, &c1);
        sincosf(0.5f * p2, &s2, &c2);
        float2 U[4], M[4];
        if (l < NLAYERS) {
            // U = Rz(p2) * Ry(p1) * Rx(p0)
            float2 RX[4] = { {c0, 0.f}, {0.f, -s0}, {0.f, -s0}, {c0, 0.f} };
            float2 RY[4] = { {c1, 0.f}, {-s1, 0.f}, {s1, 0.f}, {c1, 0.f} };
            float2 RZ[4] = { {c2, -s2}, {0.f, 0.f}, {0.f, 0.f}, {c2, s2} };
            mat2mul(RY, RX, M);
            mat2mul(RZ, M, U);
        } else {
            // U = Ry(p2) * Rz(p1) * Ry(p0)
            float2 RY0[4] = { {c0, 0.f}, {-s0, 0.f}, {s0, 0.f}, {c0, 0.f} };
            float2 RZ1[4] = { {c1, -s1}, {0.f, 0.f}, {0.f, 0.f}, {c1, s1} };
            float2 RY2[4] = { {c2, 0.f}, {-s2, 0.f}, {s2, 0.f}, {c2, 0.f} };
            mat2mul(RZ1, RY0, M);
            mat2mul(RY2, M, U);
        }
        gmat[tid * 4 + 0] = U[0];
        gmat[tid * 4 + 1] = U[1];
        gmat[tid * 4 + 2] = U[2];
        gmat[tid * 4 + 3] = U[3];
    }

    // ---- load x in C layout (i = 16*tid + j), compute sum of squares ----
    const float* xb = x + (size_t)b * DIM;
    float2 r[16];
    float ss = 0.f;
    {
        const float4* xv = reinterpret_cast<const float4*>(xb + 16 * tid);
        #pragma unroll
        for (int k = 0; k < 4; ++k) {
            float4 v = xv[k];
            r[k * 4 + 0] = make_float2(v.x, 0.f);
            r[k * 4 + 1] = make_float2(v.y, 0.f);
            r[k * 4 + 2] = make_float2(v.z, 0.f);
            r[k * 4 + 3] = make_float2(v.w, 0.f);
            ss += v.x * v.x + v.y * v.y + v.z * v.z + v.w * v.w;
        }
    }
    #pragma unroll
    for (int off = 32; off > 0; off >>= 1) ss += __shfl_down(ss, off, 64);
    if ((tid & 63) == 0) red[tid >> 6] = ss;
    __syncthreads();   // covers gmat + red

    const float total = red[0] + red[1] + red[2] + red[3];
    const float inv = 1.0f / sqrtf(sqrtf(total) + 1e-12f);
    #pragma unroll
    for (int j = 0; j < 16; ++j) { r[j].x *= inv; }

    // per-thread layout constants
    const int cxor = (tid & 7) << 1;                     // C-layout slot xor
    const int bbase = (tid >> 4) << 8;                   // B-layout base
    const int tl = tid & 15;                             // B-layout low bits
    const int tA = tid ^ (((tid >> 4) & 7) << 1);        // A-layout slot low byte

    // ---- circuit ----
    for (int l = 0; l < NLAYERS + 1; ++l) {
        const int goff = 12 * l;

        // phase C: bits 0-3 (qubits 11..8)
        apply_phase<0>(r, gmat, goff);

        // transpose C -> B
        #pragma unroll
        for (int j = 0; j < 16; j += 2) {
            *reinterpret_cast<float4*>(&st[16 * tid + (j ^ cxor)]) =
                make_float4(r[j].x, r[j].y, r[j + 1].x, r[j + 1].y);
        }
        __syncthreads();
        #pragma unroll
        for (int j = 0; j < 16; ++j) {
            r[j] = st[bbase | (j << 4) | (tl ^ ((j & 7) << 1))];
        }
        __syncthreads();

        // phase B: bits 4-7 (qubits 7..4)
        apply_phase<4>(r, gmat, goff);

        // transpose B -> A
        #pragma unroll
        for (int j = 0; j < 16; ++j) {
            st[bbase | (j << 4) | (tl ^ ((j & 7) << 1))] = r[j];
        }
        __syncthreads();
        #pragma unroll
        for (int j = 0; j < 16; ++j) {
            r[j] = st[(j << 8) | tA];
        }
        __syncthreads();

        // phase A: bits 8-11 (qubits 3..0)
        apply_phase<8>(r, gmat, goff);

        if (l == NLAYERS) break;   // final layer: no ring of CNOTs

        // ring-of-CNOT permutation fused into transpose A -> C:
        // new[i] = old[y(i)], y = i ^ (i>>1) ^ ((i&1)*0xC00)
        #pragma unroll
        for (int j = 0; j < 16; ++j) {
            st[(j << 8) | tA] = r[j];
        }
        __syncthreads();
        #pragma unroll
        for (int j = 0; j < 16; ++j) {
            const int i = 16 * tid + j;
            int y = i ^ (i >> 1);
            y ^= (i & 1) * 0xC00;
            r[j] = st[y ^ ((y >> 3) & 14)];
        }
        __syncthreads();
    }

    // ---- store real part from A layout: i = (j<<8) | tid -> coalesced ----
    float* ob = out + (size_t)b * DIM;
    #pragma unroll
    for (int j = 0; j < 16; ++j) {
        ob[(j << 8) | tid] = r[j].x;
    }
}

extern "C" void kernel_launch(void* const* d_in, const int* in_sizes, int n_in,
                              void* d_out, int out_size, void* d_ws, size_t ws_size,
                              hipStream_t stream) {
    const float* x = (const float*)d_in[0];      // [1024, 4096] f32
    const float* w = (const float*)d_in[1];      // [216] f32
    float* out = (float*)d_out;                  // [1024, 4096] f32
    qsim_kernel<<<dim3(1024), dim3(TPB), 0, stream>>>(x, w, out);
}